// Round 7
// baseline (2525.555 us; speedup 1.0000x reference)
//
#include <hip/hip_runtime.h>

// ---------------------------------------------------------------------------
// Transformer decoder (B=8,S=512,D=512,H=8,DH=64,F=2048,L=6,V=32000), MI355X.
// bf16 MFMA (16x16x32) GEMMs, m97-style tile + BK=64, global_load_lds staging,
// both-sides XOR slot swizzle; fp32 LN/residual glue.
// R3: QKV batched into one 384-block dispatch (grid under-fill fix).
// R4: BN=64 GEMM variant (WIDE=false) for O-proj/W2/PV.
// R5: softmax fused: QK writes exp(s*scale) (causal-masked), PV normalizes.
// R6: rowsum fused into QK epilogue (shfl-reduce + atomicAdd, flag 32);
//     PV divides by sum (flag 16). Bijective XCD chunk-swizzle on unembed.
// ---------------------------------------------------------------------------

typedef unsigned short u16;
typedef __attribute__((ext_vector_type(8))) short short8;    // bf16 MFMA frag
typedef __attribute__((ext_vector_type(4))) float f32x4;     // MFMA acc frag
typedef __attribute__((ext_vector_type(8))) unsigned short ushort8;

#define LDS_AS __attribute__((address_space(3)))
#define GLB_AS __attribute__((address_space(1)))

__device__ __forceinline__ u16 f2bf(float f) {
  union { float f; unsigned u; } v; v.f = f;
  unsigned r = v.u + 0x7fffu + ((v.u >> 16) & 1u);
  return (u16)(r >> 16);
}
__device__ __forceinline__ float bf2f(u16 b) {
  union { unsigned u; float f; } v; v.u = ((unsigned)b) << 16;
  return v.f;
}

// ---------------------------------------------------------------------------
// GEMM: C[M,N] = A[M,K](bf16) * Bt[N,K]^T(bf16) (+bias) (+epilogue).
// Batched via blockIdx.z -> (zb = z/div, zh = z%div) strided offsets.
// A2: alternate A base when zh>0 (QKV batching); bias2/bias3 for zh==1/2.
// flags: 1=relu, 2=store fp32, 4=store bf16,
//        8 = exp(s*0.125) epilogue (QK; with cskip: mask c>q, skip dead tiles)
//        16= divide by rowsum[z*512+row] (PV normalization)
//        32= accumulate fp32 row sums via shfl-reduce + atomicAdd (QK)
// ckend!=0: truncate K loop at bm+128 (causal PV; beyond is exact zeros).
// swz!=0: bijective XCD chunk-swizzle of (bx,by) (requires nwg%8==0).
// WIDE=true : 128x128 tile, 2x2 waves of 64x64, acc[4][4].
// WIDE=false: 128x64  tile, 4x1 waves of 32x64, acc[2][4], lB 64 rows.
// ---------------------------------------------------------------------------
struct GemmP {
  const u16* A; const u16* Bt; const float* bias;
  float* Cf; u16* Cb;
  int M, N, K, lda, ldb, ldc;
  long sAb, sAh, sBb, sBh, sCb, sCh;
  int div, flags;
  const u16* A2; const float* bias2; const float* bias3;
  int cskip, ckend; float* rowsum; int swz;
};

template <bool WIDE>
__global__ __launch_bounds__(256)
void gemm_bt(GemmP p) {
  constexpr int MIs   = WIDE ? 4 : 2;     // row fragments per wave
  constexpr int BROWS = WIDE ? 128 : 64;  // B-tile rows (= BN)
  __shared__ u16 lA[128 * 64];            // slot-swizzled [row][64]
  __shared__ u16 lB[BROWS * 64];
  const int tid = threadIdx.x;
  const int wid = tid >> 6;
  const int lane = tid & 63;
  const int z = blockIdx.z;
  const int zb = z / p.div;
  const int zh = z - zb * p.div;
  int bx = blockIdx.x, by = blockIdx.y;
  if (p.swz) {                            // XCD chunk swizzle (nwg%8==0)
    int nx = gridDim.x;
    int wg = bx + nx * by;
    int nwg = nx * gridDim.y;
    int wg2 = (wg & 7) * (nwg >> 3) + (wg >> 3);
    bx = wg2 % nx; by = wg2 / nx;
  }
  const int bm = bx * 128;
  const int bn = by * BROWS;
  if (p.cskip && bn >= bm + 128) return;  // fully-masked causal QK tile
  const u16* Abase = (p.A2 && zh > 0) ? p.A2 : p.A;
  const u16* Ab = Abase + (long)zb * p.sAb + (long)zh * p.sAh;
  const u16* Bb = p.Bt + (long)zb * p.sBb + (long)zh * p.sBh;
  const int wrow = WIDE ? (wid >> 1) * 64 : wid * 32;   // wave row base
  const int wcol = WIDE ? (wid & 1) * 64 : 0;           // wave col base

  // staging: LDS linear dest (rule #21); global source pre-swizzled so the
  // 16B slot index is XORed with (row&7) -> conflict-free ds_read_b128.
  int srow[4], scol[4];
#pragma unroll
  for (int i = 0; i < 4; ++i) {
    int off = i * 4096 + wid * 1024 + lane * 16;   // byte offset in tile
    int row = off >> 7;                            // 128 B per row
    int slot = (off >> 4) & 7;                     // 16 B slot in row
    srow[i] = row;
    scol[i] = (slot ^ (row & 7)) * 8;              // element col in row
  }

  const f32x4 zero = {0.f, 0.f, 0.f, 0.f};
  f32x4 acc[MIs][4];
#pragma unroll
  for (int i = 0; i < MIs; ++i)
#pragma unroll
    for (int j = 0; j < 4; ++j) acc[i][j] = zero;

  const int kend = p.ckend ? (bm + 128 < p.K ? bm + 128 : p.K) : p.K;
  for (int kt = 0; kt < kend; kt += 64) {
#pragma unroll
    for (int i = 0; i < 4; ++i) {
      const u16* ga = Ab + (size_t)(bm + srow[i]) * p.lda + kt + scol[i];
      __builtin_amdgcn_global_load_lds((const GLB_AS void*)ga,
          (LDS_AS void*)(lA + i * 2048 + wid * 512), 16, 0, 0);
      if (WIDE || i < 2) {
        const u16* gb = Bb + (size_t)(bn + srow[i]) * p.ldb + kt + scol[i];
        __builtin_amdgcn_global_load_lds((const GLB_AS void*)gb,
            (LDS_AS void*)(lB + i * 2048 + wid * 512), 16, 0, 0);
      }
    }
    __syncthreads();   // drains vmcnt before barrier -> LDS tiles ready

    const int krow = lane >> 4;
    const int fr = lane & 15;
#pragma unroll
    for (int kh = 0; kh < 2; ++kh) {
      short8 af[MIs], bfg[4];
#pragma unroll
      for (int mi = 0; mi < MIs; ++mi) {
        int r = wrow + mi * 16 + fr;
        int slot = (kh * 4 + krow) ^ (r & 7);
        af[mi] = *(const short8*)&lA[r * 64 + slot * 8];
      }
#pragma unroll
      for (int ni = 0; ni < 4; ++ni) {
        int r = wcol + ni * 16 + fr;
        int slot = (kh * 4 + krow) ^ (r & 7);
        bfg[ni] = *(const short8*)&lB[r * 64 + slot * 8];
      }
#pragma unroll
      for (int mi = 0; mi < MIs; ++mi)
#pragma unroll
        for (int ni = 0; ni < 4; ++ni)
          acc[mi][ni] = __builtin_amdgcn_mfma_f32_16x16x32_bf16(
              af[mi], bfg[ni], acc[mi][ni], 0, 0, 0);
    }
    __syncthreads();   // protect LDS before next stage
  }

  float* Cf = (p.flags & 2) ? p.Cf + (long)zb * p.sCb + (long)zh * p.sCh : nullptr;
  u16*   Cb = (p.flags & 4) ? p.Cb + (long)zb * p.sCb + (long)zh * p.sCh : nullptr;
  const float* bp = p.bias;
  if (zh == 1 && p.bias2) bp = p.bias2;
  else if (zh == 2 && p.bias3) bp = p.bias3;
  const int fr = lane & 15;
  const int rq = (lane >> 4) << 2;
  float rsum[MIs][4];
  if (p.flags & 32) {
#pragma unroll
    for (int mi = 0; mi < MIs; ++mi)
#pragma unroll
      for (int r = 0; r < 4; ++r) rsum[mi][r] = 0.f;
  }
#pragma unroll
  for (int ni = 0; ni < 4; ++ni) {
    int col = bn + wcol + ni * 16 + fr;
    if (col >= p.N) continue;                 // predicated store
    float bvv = bp ? bp[col] : 0.f;
#pragma unroll
    for (int mi = 0; mi < MIs; ++mi) {
      int row0 = bm + wrow + mi * 16 + rq;
#pragma unroll
      for (int r = 0; r < 4; ++r) {
        float v = acc[mi][ni][r] + bvv;
        if (p.flags & 1) v = fmaxf(v, 0.f);
        if (p.flags & 8) {                    // QK: p' = exp(s*scale), masked
          int qrow = row0 + r;                // q index within 512
          v = (p.cskip && col > qrow) ? 0.f : __expf(v * 0.125f);
        }
        if (p.flags & 32) rsum[mi][r] += v;   // fp32 row-sum accumulation
        if (p.flags & 16)                     // PV: normalize by row sum
          v /= p.rowsum[(size_t)z * 512 + row0 + r];
        size_t idx = (size_t)(row0 + r) * p.ldc + col;
        if (p.flags & 2) Cf[idx] = v;
        if (p.flags & 4) Cb[idx] = f2bf(v);
      }
    }
  }
  if (p.flags & 32) {
    // reduce over the 16 fr-lanes that share each output row (C/D layout:
    // col=lane&15, row=(lane>>4)*4+r), then one atomic per row per wave.
#pragma unroll
    for (int mi = 0; mi < MIs; ++mi)
#pragma unroll
      for (int r = 0; r < 4; ++r) {
        float s = rsum[mi][r];
        s += __shfl_xor(s, 1);
        s += __shfl_xor(s, 2);
        s += __shfl_xor(s, 4);
        s += __shfl_xor(s, 8);
        if (fr == 0)
          atomicAdd(p.rowsum + (size_t)z * 512 + bm + wrow + mi * 16 + rq + r, s);
      }
  }
}

// ---------------------------------------------------------------------------
// glue kernels
// ---------------------------------------------------------------------------

// zero a float buffer (n multiple of 4)
__global__ __launch_bounds__(256)
void zero_f(float* __restrict__ p, int n) {
  int i = (blockIdx.x * 256 + threadIdx.x) * 4;
  if (i < n) { float4 z = {0.f, 0.f, 0.f, 0.f}; *(float4*)(p + i) = z; }
}

// flat fp32 -> bf16 convert (n multiple of 8)
__global__ __launch_bounds__(256)
void cvt_bf16(const float* __restrict__ in, u16* __restrict__ out, long n) {
  long i = ((long)blockIdx.x * 256 + threadIdx.x) * 8;
  if (i >= n) return;
  float4 a = *(const float4*)(in + i);
  float4 b = *(const float4*)(in + i + 4);
  ushort8 o;
  o[0] = f2bf(a.x); o[1] = f2bf(a.y); o[2] = f2bf(a.z); o[3] = f2bf(a.w);
  o[4] = f2bf(b.x); o[5] = f2bf(b.y); o[6] = f2bf(b.z); o[7] = f2bf(b.w);
  *(ushort8*)(out + i) = o;
}

// 64x64-tile transpose+convert: in fp32 [z][R][C] -> out bf16 [z][C][R]
__global__ __launch_bounds__(256)
void tcvt(const float* __restrict__ in, u16* __restrict__ out,
          int R, int C, long inStride, long outStride) {
  __shared__ u16 t[64][65];
  const float* ip = in + (size_t)blockIdx.z * inStride;
  u16* op = out + (size_t)blockIdx.z * outStride;
  int r0 = blockIdx.x * 64, c0 = blockIdx.y * 64;
  for (int i = threadIdx.x; i < 4096; i += 256) {
    int r = i >> 6, c = i & 63;
    t[r][c] = f2bf(ip[(size_t)(r0 + r) * C + c0 + c]);
  }
  __syncthreads();
  for (int i = threadIdx.x; i < 4096; i += 256) {
    int c = i >> 6, r = i & 63;
    op[(size_t)(c0 + c) * R + r0 + r] = t[r][c];
  }
}

// V [b][s][h*64+dh] bf16  ->  vT [(b*8+h)][128(pad)][512] bf16 (rows 0..63)
__global__ __launch_bounds__(256)
void vtrans(const u16* __restrict__ v, u16* __restrict__ vT) {
  __shared__ u16 t[64][65];
  int z = blockIdx.z, b = z >> 3, h = z & 7;
  int s0 = blockIdx.x * 64;
  for (int i = threadIdx.x; i < 4096; i += 256) {
    int si = i >> 6, d = i & 63;
    t[si][d] = v[(size_t)(b * 512 + s0 + si) * 512 + h * 64 + d];
  }
  __syncthreads();
  for (int i = threadIdx.x; i < 4096; i += 256) {
    int d = i >> 6, si = i & 63;
    vT[((size_t)z * 128 + d) * 512 + s0 + si] = t[si][d];
  }
}

// embedding gather: x = emb[target], fp32 + bf16 mirrors. one wave per row.
__global__ __launch_bounds__(256)
void gather_embed(const float* __restrict__ emb, const int* __restrict__ tgt,
                  float* __restrict__ xf, u16* __restrict__ xb) {
  int row = blockIdx.x * 4 + (threadIdx.x >> 6);
  int lane = threadIdx.x & 63;
  int t = tgt[row];
  const float4* src = (const float4*)(emb + (size_t)t * 512);
  float4* dst = (float4*)(xf + (size_t)row * 512);
  float4 a = src[lane * 2], b = src[lane * 2 + 1];
  dst[lane * 2] = a; dst[lane * 2 + 1] = b;
  ushort8 o;
  o[0] = f2bf(a.x); o[1] = f2bf(a.y); o[2] = f2bf(a.z); o[3] = f2bf(a.w);
  o[4] = f2bf(b.x); o[5] = f2bf(b.y); o[6] = f2bf(b.z); o[7] = f2bf(b.w);
  *(ushort8*)(xb + (size_t)row * 512 + lane * 8) = o;
}

// x = LN(a + r); writes fp32 x (in-place safe) + bf16 mirror. wave per row.
__global__ __launch_bounds__(256)
void add_ln(const float* __restrict__ a, const float* __restrict__ r,
            const float* __restrict__ g, const float* __restrict__ bb,
            float* __restrict__ xo, u16* __restrict__ xb) {
  int row = blockIdx.x * 4 + (threadIdx.x >> 6);
  int lane = threadIdx.x & 63;
  const float4* pa = (const float4*)(a + (size_t)row * 512) + lane * 2;
  const float4* pr = (const float4*)(r + (size_t)row * 512) + lane * 2;
  float4 x0 = pa[0], x1 = pa[1], r0 = pr[0], r1 = pr[1];
  float v[8] = { x0.x + r0.x, x0.y + r0.y, x0.z + r0.z, x0.w + r0.w,
                 x1.x + r1.x, x1.y + r1.y, x1.z + r1.z, x1.w + r1.w };
  float s = 0.f;
#pragma unroll
  for (int j = 0; j < 8; ++j) s += v[j];
#pragma unroll
  for (int o = 32; o >= 1; o >>= 1) s += __shfl_xor(s, o);
  float mu = s * (1.f / 512.f);
  float ss = 0.f;
#pragma unroll
  for (int j = 0; j < 8; ++j) { v[j] -= mu; ss += v[j] * v[j]; }
#pragma unroll
  for (int o = 32; o >= 1; o >>= 1) ss += __shfl_xor(ss, o);
  float rs = rsqrtf(ss * (1.f / 512.f) + 1e-5f);
  const float4* pg = (const float4*)g + lane * 2;
  const float4* pb = (const float4*)bb + lane * 2;
  float4 g0 = pg[0], g1 = pg[1], b0 = pb[0], b1 = pb[1];
  float y[8];
  y[0] = v[0] * rs * g0.x + b0.x; y[1] = v[1] * rs * g0.y + b0.y;
  y[2] = v[2] * rs * g0.z + b0.z; y[3] = v[3] * rs * g0.w + b0.w;
  y[4] = v[4] * rs * g1.x + b1.x; y[5] = v[5] * rs * g1.y + b1.y;
  y[6] = v[6] * rs * g1.z + b1.z; y[7] = v[7] * rs * g1.w + b1.w;
  float4* po = (float4*)(xo + (size_t)row * 512) + lane * 2;
  float4 o0 = { y[0], y[1], y[2], y[3] }, o1 = { y[4], y[5], y[6], y[7] };
  po[0] = o0; po[1] = o1;
  ushort8 ob;
#pragma unroll
  for (int j = 0; j < 8; ++j) ob[j] = f2bf(y[j]);
  *(ushort8*)(xb + (size_t)row * 512 + lane * 8) = ob;
}

// ---------------------------------------------------------------------------
// host
// ---------------------------------------------------------------------------
static void gemm_w(hipStream_t st, bool wide, const void* A, const void* Bt,
                   const float* bias, void* Cf, void* Cb, int M, int N, int K,
                   int lda, int ldb, int ldc,
                   long sAb, long sAh, long sBb, long sBh, long sCb, long sCh,
                   int div_, int flags, int batches,
                   int cskip = 0, int ckend = 0, float* rowsum = nullptr,
                   int swz = 0) {
  GemmP p{ (const u16*)A, (const u16*)Bt, bias, (float*)Cf, (u16*)Cb,
           M, N, K, lda, ldb, ldc, sAb, sAh, sBb, sBh, sCb, sCh, div_, flags,
           nullptr, nullptr, nullptr, cskip, ckend, rowsum, swz };
  if (wide) {
    dim3 g(M / 128, (N + 127) / 128, batches);
    gemm_bt<true><<<g, dim3(256), 0, st>>>(p);
  } else {
    dim3 g(M / 128, (N + 63) / 64, batches);
    gemm_bt<false><<<g, dim3(256), 0, st>>>(p);
  }
}

// QKV-batched projection: z=0 -> Q=A0*Wq, z=1 -> K=A12*Wk, z=2 -> V=A12*Wv.
static void gemm_qkv(hipStream_t st, const u16* A0, const u16* A12,
                     const u16* WqT, long sW,
                     const float* bq, const float* bk, const float* bv,
                     u16* qout, long sC) {
  GemmP p{ A0, WqT, bq, nullptr, qout,
           4096, 512, 512, 512, 512, 512,
           0, 0, 0, sW, 0, sC, 3, 4,
           A12, bk, bv, 0, 0, nullptr, 0 };
  gemm_bt<true><<<dim3(32, 4, 3), dim3(256), 0, st>>>(p);
}

extern "C" void kernel_launch(void* const* d_in, const int* in_sizes, int n_in,
                              void* d_out, int out_size, void* d_ws, size_t ws_size,
                              hipStream_t stream) {
  const float* encoded = (const float*)d_in[0];
  const int*   target  = (const int*)d_in[1];
  const float* embW    = (const float*)d_in[2];
  const float* Wsrc[8] = { (const float*)d_in[3],  (const float*)d_in[5],
                           (const float*)d_in[7],  (const float*)d_in[9],
                           (const float*)d_in[11], (const float*)d_in[13],
                           (const float*)d_in[15], (const float*)d_in[17] };
  const float* bsrc[8] = { (const float*)d_in[4],  (const float*)d_in[6],
                           (const float*)d_in[8],  (const float*)d_in[10],
                           (const float*)d_in[12], (const float*)d_in[14],
                           (const float*)d_in[16], (const float*)d_in[18] };
  const float* W1 = (const float*)d_in[19]; const float* b1 = (const float*)d_in[20];
  const float* W2 = (const float*)d_in[21]; const float* b2 = (const float*)d_in[22];
  const float* ln_g = (const float*)d_in[23]; const float* ln_b = (const float*)d_in[24];

  char* w = (char*)d_ws;
  auto alloc = [&](size_t bytes) -> char* {
    char* p = w; w += (bytes + 255) & ~(size_t)255; return p;
  };
  u16* emb_b = (u16*)alloc(32000L * 512 * 2);            // emb bf16 [V][D]
  u16* WT[8];
  for (int f = 0; f < 8; ++f) WT[f] = (u16*)alloc(6L * 512 * 512 * 2);  // [L][N][K]
  u16* W1T = (u16*)alloc(6L * 2048 * 512 * 2);           // [L][F][D]
  u16* W2T = (u16*)alloc(6L * 512 * 2048 * 2);           // [L][D][F]
  u16* enc_b = (u16*)alloc(4096L * 512 * 2);
  float* xf = (float*)alloc(4096L * 512 * 4);
  u16* xb  = (u16*)alloc(4096L * 512 * 2);
  u16* qb  = (u16*)alloc(4096L * 512 * 2);
  u16* kb  = (u16*)alloc(4096L * 512 * 2);
  u16* vb  = (u16*)alloc(4096L * 512 * 2);
  u16* vT  = (u16*)alloc(64L * 128 * 512 * 2);           // padded to 128 rows
  float* of = (float*)alloc(4096L * 512 * 4);            // O-proj / FFN out
  u16* probs = (u16*)alloc(64L * 512 * 512 * 2);         // p' = exp scores bf16
  float* sums = (float*)alloc(64L * 512 * 4);            // rowsum [bh][512]
  // lifetime unions (desk-verified disjoint):
  u16* attn = vb;              // PV output; vb dead after vtrans
  u16* h1 = probs;             // FFN hidden [4096][2048]; probs attn-only
  // exact-by-construction strides (bump allocator, 256-aligned sizes):
  const long sW_qkv = (long)(WT[1] - WT[0]);   // == WT[2]-WT[1] == WT[5]-WT[4]
  const long sC_qkv = (long)(kb - qb);         // == vb - kb
  (void)ws_size; (void)n_in; (void)in_sizes; (void)out_size;

  // ---- one-time-per-call conversions ----
  cvt_bf16<<<8000, 256, 0, stream>>>(embW, emb_b, 16384000L);
  cvt_bf16<<<1024, 256, 0, stream>>>(encoded, enc_b, 2097152L);
  gather_embed<<<1024, 256, 0, stream>>>(embW, target, xf, xb);
  for (int f = 0; f < 8; ++f)
    tcvt<<<dim3(8, 8, 6), 256, 0, stream>>>(Wsrc[f], WT[f], 512, 512, 262144L, 262144L);
  tcvt<<<dim3(8, 32, 6), 256, 0, stream>>>(W1, W1T, 512, 2048, 1048576L, 1048576L);
  tcvt<<<dim3(32, 8, 6), 256, 0, stream>>>(W2, W2T, 2048, 512, 1048576L, 1048576L);

  for (int l = 0; l < 6; ++l) {
    const float* bq_m = bsrc[0] + l * 512;
    const float* bk_m = bsrc[1] + l * 512;
    const float* bv_m = bsrc[2] + l * 512;
    const u16* wo_m = WT[3] + l * 262144; const float* bo_m = bsrc[3] + l * 512;
    const float* bq_s = bsrc[4] + l * 512;
    const float* bk_s = bsrc[5] + l * 512;
    const float* bv_s = bsrc[6] + l * 512;
    const u16* wo_s = WT[7] + l * 262144; const float* bo_s = bsrc[7] + l * 512;

    // ======== cross-attention (K/V from encoded) ========
    gemm_qkv(stream, xb, enc_b, WT[0] + l * 262144, sW_qkv,
             bq_m, bk_m, bv_m, qb, sC_qkv);
    vtrans<<<dim3(8, 1, 64), 256, 0, stream>>>(vb, vT);
    zero_f<<<32, 256, 0, stream>>>(sums, 32768);
    // p' = exp(QK^T*scale); row sums accumulated in-epilogue (flags 4|8|32)
    gemm_w(stream, true, qb, kb, nullptr, nullptr, probs, 512, 512, 64,
           512, 512, 512, 262144, 64, 262144, 64, 2097152, 262144, 8,
           4 | 8 | 32, 64, 0, 0, sums);
    // attn = (p' V) / sums  (BN=64 variant; attn aliases dead vb)
    gemm_w(stream, false, probs, vT, nullptr, nullptr, attn, 512, 64, 512,
           512, 512, 512, 2097152, 262144, 524288, 65536, 262144, 64, 8,
           4 | 16, 64, 0, 0, sums);
    gemm_w(stream, false, attn, wo_m, bo_m, of, nullptr, 4096, 512, 512,
           512, 512, 512, 0, 0, 0, 0, 0, 0, 1, 2, 1);
    add_ln<<<1024, 256, 0, stream>>>(xf, of, ln_g, ln_b, xf, xb);

    // ======== self-attention (causal) ========
    gemm_qkv(stream, xb, xb, WT[4] + l * 262144, sW_qkv,
             bq_s, bk_s, bv_s, qb, sC_qkv);
    vtrans<<<dim3(8, 1, 64), 256, 0, stream>>>(vb, vT);
    zero_f<<<32, 256, 0, stream>>>(sums, 32768);
    // p' = exp(QK^T*scale), causal-masked; dead tiles skipped; sums fused
    gemm_w(stream, true, qb, kb, nullptr, nullptr, probs, 512, 512, 64,
           512, 512, 512, 262144, 64, 262144, 64, 2097152, 262144, 8,
           4 | 8 | 32, 64, 1, 0, sums);
    // attn = (p' V) / sums, K truncated at bm+128 (exact: beyond is zeros)
    gemm_w(stream, false, probs, vT, nullptr, nullptr, attn, 512, 64, 512,
           512, 512, 512, 2097152, 262144, 524288, 65536, 262144, 64, 8,
           4 | 16, 64, 0, 1, sums);
    gemm_w(stream, false, attn, wo_s, bo_s, of, nullptr, 4096, 512, 512,
           512, 512, 512, 0, 0, 0, 0, 0, 0, 1, 2, 1);
    add_ln<<<1024, 256, 0, stream>>>(xf, of, ln_g, ln_b, xf, xb);

    // ======== FFN: h = relu(relu(x W1 + b1) W2 + b2) ========
    gemm_w(stream, true, xb, W1T + l * 1048576, b1 + l * 2048, nullptr, h1,
           4096, 2048, 512, 512, 512, 2048, 0, 0, 0, 0, 0, 0, 1, 4 | 1, 1);
    gemm_w(stream, false, h1, W2T + l * 1048576, b2 + l * 512, of, nullptr,
           4096, 512, 2048, 2048, 2048, 512, 0, 0, 0, 0, 0, 0, 1, 2 | 1, 1);
    add_ln<<<1024, 256, 0, stream>>>(xf, of, ln_g, ln_b, xf, xb);
  }

  // ======== unembed: logits = x @ emb^T -> d_out fp32, XCD-swizzled ========
  gemm_w(stream, true, xb, emb_b, nullptr, d_out, nullptr, 4096, 32000, 512,
         512, 512, 32000, 0, 0, 0, 0, 0, 0, 1, 2, 1, 0, 0, nullptr, 1);
}